// Round 5
// baseline (215.229 us; speedup 1.0000x reference)
//
#include <hip/hip_runtime.h>
#include <stdint.h>

// Problem constants (fixed by the reference): n=8, c=16, H=W=512.
#define NIMG 8
#define NCLS 16
#define HW   262144            // 512*512 = 2^18 pixels per image
#define PXB  512               // pixels per block tile (32 KB LDS -> 4 blocks/CU)
#define NBLK 4096              // (NIMG*HW)/PXB ; 512 blocks per image

// Async global->LDS, 16B per lane, no destination VGPRs.
// LDS dest semantics: wave-uniform base + lane*16 (m104/m108).
__device__ __forceinline__ void g2lds16(const float* g, float* l) {
    __builtin_amdgcn_global_load_lds(
        (const __attribute__((address_space(1))) unsigned int*)g,
        (__attribute__((address_space(3))) unsigned int*)l,
        16, 0, 0);
}

// ---------------------------------------------------------------------------
// Main pass. Block b owns 512 consecutive pixels of one image.
// Stage: wave w loads channels [4w,4w+4), 2 KB strip each, as 2x 1-KB LDS-DMA
//        instructions -> 8 outstanding loads per wave, 16 waves per CU.
// Compute: two LDS passes (max+gather, sum-exp) at 2 px/thread (ds_read_b64).
// Accumulate per-block (class-sum, class-count) bins in LDS, write non-atomic
// per-block partials (c-major).
// ---------------------------------------------------------------------------
__global__ __launch_bounds__(256) void dwce_main(const float* __restrict__ pred,
                                                 const int* __restrict__ tgt,
                                                 float* __restrict__ partials) {
    __shared__ float tile[NCLS * PXB];   // 32 KB: [c][512 px]
    __shared__ float s_bin[32];          // [0..15] sum(lp_t), [16..31] count
    const int tid = threadIdx.x;

    const int b = blockIdx.x;
    const long long px0 = (long long)b * PXB;      // tile start (one image)
    const int n_img = (int)(px0 >> 18);
    const int hw0   = (int)(px0 & (HW - 1));
    const float* base = pred + (size_t)n_img * NCLS * HW + hw0;

    const int w    = tid >> 6;           // wave 0..3
    const int lane = tid & 63;
    const int loff = lane * 4;           // lane float offset (16 B per lane)

    // Wave w stages channels 4w..4w+3; each 2-KB strip = 2 x 1-KB DMA loads.
#pragma unroll
    for (int j = 0; j < 4; ++j) {
        const int c = w * 4 + j;
        const float* gc = base + (size_t)c * HW;
        float* lc = &tile[c * PXB];
        g2lds16(gc + loff,       lc + loff);
        g2lds16(gc + 256 + loff, lc + 256 + loff);
    }

    if (tid < 32) s_bin[tid] = 0.0f;
    // Targets for this thread's 2 pixels.
    const int2 t2 = *(const int2*)(tgt + px0 + tid * 2);

    __syncthreads();   // vmcnt(0) drain + barrier

    const int p = tid * 2;               // this thread's 2 contiguous pixels

    // Pass 1: max over channels + gather logit at target class.
    float2 m  = make_float2(-3.0e38f, -3.0e38f);
    float2 xt = make_float2(0.f, 0.f);
#pragma unroll
    for (int c = 0; c < NCLS; ++c) {
        const float2 v = *(const float2*)&tile[c * PXB + p];  // ds_read_b64
        m.x = fmaxf(m.x, v.x);
        m.y = fmaxf(m.y, v.y);
        if (t2.x == c) xt.x = v.x;   // -> v_cndmask, no divergence
        if (t2.y == c) xt.y = v.y;
    }

    // Pass 2: sum of exp(v - m).
    float2 s = make_float2(0.f, 0.f);
#pragma unroll
    for (int c = 0; c < NCLS; ++c) {
        const float2 v = *(const float2*)&tile[c * PXB + p];
        s.x += __expf(v.x - m.x);
        s.y += __expf(v.y - m.y);
    }

    const float lp0 = xt.x - (m.x + __logf(s.x));
    const float lp1 = xt.y - (m.y + __logf(s.y));

    atomicAdd(&s_bin[t2.x], lp0);
    atomicAdd(&s_bin[t2.y], lp1);
    atomicAdd(&s_bin[16 + t2.x], 1.0f);
    atomicAdd(&s_bin[16 + t2.y], 1.0f);

    __syncthreads();
    if (tid < 32)   // non-atomic per-block partials, c-major: partials[c][block]
        partials[(size_t)tid * NBLK + b] = s_bin[tid];
}

// ---------------------------------------------------------------------------
// Finalize: reduce 4096 block-partials per bin, build w_class from global
// counts, compute -mean_n(num/den). Single block, 256 threads.
// Image n owns blocks [n*512, (n+1)*512) -> contiguous 512 floats per (c,n).
// ---------------------------------------------------------------------------
__global__ __launch_bounds__(256) void dwce_final(const float* __restrict__ ws,
                                                  float* __restrict__ out) {
    __shared__ float tot[32][NIMG];   // [c(0..31)][n]
    __shared__ float wcl[NCLS];
    __shared__ float ratio[NIMG];
    const int tid = threadIdx.x;
    const int c = tid >> 3;           // 0..31
    const int n = tid & 7;            // 0..7

    const float4* p = (const float4*)(ws + (size_t)c * NBLK + n * 512);
    float4 a = make_float4(0.f, 0.f, 0.f, 0.f);
#pragma unroll 8
    for (int k = 0; k < 128; ++k) {
        float4 q = p[k];
        a.x += q.x; a.y += q.y; a.z += q.z; a.w += q.w;
    }
    tot[c][n] = (a.x + a.y) + (a.z + a.w);
    __syncthreads();

    if (tid < NCLS) {
        float g = 0.f;
#pragma unroll
        for (int i = 0; i < NIMG; ++i) g += tot[NCLS + tid][i];   // global count
        wcl[tid] = (g > 0.f) ? 1.0f / (g * (float)NCLS) : 0.0f;
    }
    __syncthreads();
    if (tid < NIMG) {
        float num = 0.f, den = 0.f;
#pragma unroll
        for (int c2 = 0; c2 < NCLS; ++c2) {
            num += tot[c2][tid] * wcl[c2];
            den += tot[NCLS + c2][tid] * wcl[c2];
        }
        ratio[tid] = num / den;
    }
    __syncthreads();
    if (tid == 0) {
        float r = 0.f;
#pragma unroll
        for (int i = 0; i < NIMG; ++i) r += ratio[i];
        out[0] = -r * (1.0f / (float)NIMG);
    }
}

extern "C" void kernel_launch(void* const* d_in, const int* in_sizes, int n_in,
                              void* d_out, int out_size, void* d_ws, size_t ws_size,
                              hipStream_t stream) {
    const float* pred = (const float*)d_in[0];
    const int*   tgt  = (const int*)d_in[1];
    // d_in[2] (weights) is ignored by the reference.
    float* out = (float*)d_out;
    float* ws  = (float*)d_ws;   // 32*NBLK floats = 512 KB, fully overwritten

    dwce_main<<<NBLK, 256, 0, stream>>>(pred, tgt, ws);
    dwce_final<<<1, 256, 0, stream>>>(ws, out);
}